// Round 10
// baseline (277.398 us; speedup 1.0000x reference)
//
#include <hip/hip_runtime.h>

// MSE over remapped (norms, labels):
//   label==1: n *= 10, target = 10
//   label==2: n *= 5,  target = 20
//   else:     n *= 1,  target = 0
// out[0] = mean((n - target)^2) over 4096*8192 f32 elements.
//
// Ladder: naive grid-stride 105us -> x4 unroll 101us -> +nt ~84us -> x8
// flat -> two-stage flat -> contiguous 64KB/block chunks 250.6us total
// (stage1 ~76us, ~3.5 TB/s). Round-10 A/B: CACHED loads + chunking.
// Hypothesis: nt bypasses the L3, discarding ~134MB of restore-copy
// residency that cached loads were shown to hit (FETCH_SIZE=134MB, r2/r3).

typedef float f4 __attribute__((ext_vector_type(4)));

#define NBLOCKS 2048
#define NTHREADS 256

__device__ __forceinline__ float remap_sq(float n, float lab) {
    float sn  = (lab == 1.0f) ? 10.0f : ((lab == 2.0f) ? 5.0f : 1.0f);
    float tgt = lab * 10.0f;                 // 0 / 10 / 20
    float d   = fmaf(n, sn, -tgt);
    return d * d;
}

__device__ __forceinline__ float remap_sq4(f4 n, f4 l) {
    return remap_sq(n.x, l.x) + remap_sq(n.y, l.y)
         + remap_sq(n.z, l.z) + remap_sq(n.w, l.w);
}

__global__ __launch_bounds__(NTHREADS) void mse_remap_stage1(
    const float* __restrict__ norms,
    const float* __restrict__ labels,
    float* __restrict__ partials,        // d_ws, one slot per block
    size_t n4, size_t n, size_t chunk)   // chunk = f4 elements per block
{
    const f4* np4 = reinterpret_cast<const f4*>(norms);
    const f4* lp4 = reinterpret_cast<const f4*>(labels);

    size_t base = (size_t)blockIdx.x * chunk;
    size_t end  = base + chunk; if (end > n4) end = n4;

    float acc = 0.0f;
    size_t i = base + threadIdx.x;

    // Batch 8 block-iterations: 16 float4 loads in flight, spanning a
    // contiguous 32KB window per array. CACHED loads (vs nt in round 9) to
    // recover L3 hits on the restore-resident inputs.
    for (; i + 7 * NTHREADS < end; i += 8 * NTHREADS) {
        f4 a0 = np4[i];
        f4 a1 = np4[i + 1 * NTHREADS];
        f4 a2 = np4[i + 2 * NTHREADS];
        f4 a3 = np4[i + 3 * NTHREADS];
        f4 a4 = np4[i + 4 * NTHREADS];
        f4 a5 = np4[i + 5 * NTHREADS];
        f4 a6 = np4[i + 6 * NTHREADS];
        f4 a7 = np4[i + 7 * NTHREADS];
        f4 b0 = lp4[i];
        f4 b1 = lp4[i + 1 * NTHREADS];
        f4 b2 = lp4[i + 2 * NTHREADS];
        f4 b3 = lp4[i + 3 * NTHREADS];
        f4 b4 = lp4[i + 4 * NTHREADS];
        f4 b5 = lp4[i + 5 * NTHREADS];
        f4 b6 = lp4[i + 6 * NTHREADS];
        f4 b7 = lp4[i + 7 * NTHREADS];
        acc += remap_sq4(a0, b0);
        acc += remap_sq4(a1, b1);
        acc += remap_sq4(a2, b2);
        acc += remap_sq4(a3, b3);
        acc += remap_sq4(a4, b4);
        acc += remap_sq4(a5, b5);
        acc += remap_sq4(a6, b6);
        acc += remap_sq4(a7, b7);
    }
    // f4 remainder within chunk (not hit at this size — defensive)
    for (; i < end; i += NTHREADS) {
        f4 a = np4[i];
        f4 b = lp4[i];
        acc += remap_sq4(a, b);
    }
    // scalar global remainder (n % 4 != 0 — defensive, block 0 only)
    if (blockIdx.x == 0)
        for (size_t j = n4 * 4 + threadIdx.x; j < n; j += NTHREADS)
            acc += remap_sq(norms[j], labels[j]);

    // wave-64 butterfly reduction
#pragma unroll
    for (int off = 32; off > 0; off >>= 1)
        acc += __shfl_down(acc, off, 64);

    __shared__ float wsum[4];                // 256 threads = 4 waves
    int lane = threadIdx.x & 63;
    int wid  = threadIdx.x >> 6;
    if (lane == 0) wsum[wid] = acc;
    __syncthreads();

    if (threadIdx.x == 0)
        partials[blockIdx.x] = (wsum[0] + wsum[1]) + (wsum[2] + wsum[3]);
}

__global__ __launch_bounds__(NTHREADS) void mse_remap_stage2(
    const float* __restrict__ partials,
    float* __restrict__ out, float inv_n)
{
    // NBLOCKS=2048 floats = 512 float4; 256 threads x 2 float4 each.
    const f4* p4 = reinterpret_cast<const f4*>(partials);
    f4 v0 = p4[threadIdx.x];
    f4 v1 = p4[threadIdx.x + 256];
    float acc = (v0.x + v0.y) + (v0.z + v0.w)
              + (v1.x + v1.y) + (v1.z + v1.w);

#pragma unroll
    for (int off = 32; off > 0; off >>= 1)
        acc += __shfl_down(acc, off, 64);

    __shared__ float wsum[4];
    int lane = threadIdx.x & 63;
    int wid  = threadIdx.x >> 6;
    if (lane == 0) wsum[wid] = acc;
    __syncthreads();

    if (threadIdx.x == 0)
        out[0] = ((wsum[0] + wsum[1]) + (wsum[2] + wsum[3])) * inv_n;
}

extern "C" void kernel_launch(void* const* d_in, const int* in_sizes, int n_in,
                              void* d_out, int out_size, void* d_ws, size_t ws_size,
                              hipStream_t stream)
{
    const float* norms  = (const float*)d_in[0];
    const float* labels = (const float*)d_in[1];
    float* out      = (float*)d_out;
    float* partials = (float*)d_ws;          // 2048 floats = 8 KB scratch

    size_t n  = (size_t)in_sizes[0];         // 4096*8192 = 33,554,432
    size_t n4 = n / 4;                       // 8,388,608 f4
    size_t chunk = (n4 + NBLOCKS - 1) / NBLOCKS;   // 4096 f4 = 64 KB per block
    float inv_n = 1.0f / (float)n;

    mse_remap_stage1<<<NBLOCKS, NTHREADS, 0, stream>>>(norms, labels, partials,
                                                       n4, n, chunk);
    mse_remap_stage2<<<1, NTHREADS, 0, stream>>>(partials, out, inv_n);
}

// Round 11
// 266.272 us; speedup vs baseline: 1.0418x; 1.0418x over previous
//
#include <hip/hip_runtime.h>

// MSE over remapped (norms, labels):
//   label==1: n *= 10, target = 10
//   label==2: n *= 5,  target = 20
//   else:     n *= 1,  target = 0
// out[0] = mean((n - target)^2) over 4096*8192 f32 elements.
//
// Ladder: naive 105us -> x4 101 -> +nt ~84 -> x8 flat -> 2-stage flat ->
// chunked+nt ~75us (250.6 total) -> chunked+cached 107us (cached-path
// allocate wall ~2.5 TB/s, CONFIRMED round 10). This round: MIXED policy —
// norms nt (pure HBM stream path), labels cached (L3-hit path). The two
// request paths may overlap -> each carries 134 MB.

typedef float f4 __attribute__((ext_vector_type(4)));

#define NBLOCKS 2048
#define NTHREADS 256

__device__ __forceinline__ float remap_sq(float n, float lab) {
    float sn  = (lab == 1.0f) ? 10.0f : ((lab == 2.0f) ? 5.0f : 1.0f);
    float tgt = lab * 10.0f;                 // 0 / 10 / 20
    float d   = fmaf(n, sn, -tgt);
    return d * d;
}

__device__ __forceinline__ float remap_sq4(f4 n, f4 l) {
    return remap_sq(n.x, l.x) + remap_sq(n.y, l.y)
         + remap_sq(n.z, l.z) + remap_sq(n.w, l.w);
}

__global__ __launch_bounds__(NTHREADS) void mse_remap_stage1(
    const float* __restrict__ norms,
    const float* __restrict__ labels,
    float* __restrict__ partials,        // d_ws, one slot per block
    size_t n4, size_t n, size_t chunk)   // chunk = f4 elements per block
{
    const f4* np4 = reinterpret_cast<const f4*>(norms);
    const f4* lp4 = reinterpret_cast<const f4*>(labels);

    size_t base = (size_t)blockIdx.x * chunk;
    size_t end  = base + chunk; if (end > n4) end = n4;

    float acc = 0.0f;
    size_t i = base + threadIdx.x;

    // 8 contiguous block-iterations batched: norms via nontemporal (bypass
    // allocate, pure HBM stream), labels via cached loads (L3-hit path).
    for (; i + 7 * NTHREADS < end; i += 8 * NTHREADS) {
        f4 a0 = __builtin_nontemporal_load(&np4[i]);
        f4 a1 = __builtin_nontemporal_load(&np4[i + 1 * NTHREADS]);
        f4 a2 = __builtin_nontemporal_load(&np4[i + 2 * NTHREADS]);
        f4 a3 = __builtin_nontemporal_load(&np4[i + 3 * NTHREADS]);
        f4 a4 = __builtin_nontemporal_load(&np4[i + 4 * NTHREADS]);
        f4 a5 = __builtin_nontemporal_load(&np4[i + 5 * NTHREADS]);
        f4 a6 = __builtin_nontemporal_load(&np4[i + 6 * NTHREADS]);
        f4 a7 = __builtin_nontemporal_load(&np4[i + 7 * NTHREADS]);
        f4 b0 = lp4[i];
        f4 b1 = lp4[i + 1 * NTHREADS];
        f4 b2 = lp4[i + 2 * NTHREADS];
        f4 b3 = lp4[i + 3 * NTHREADS];
        f4 b4 = lp4[i + 4 * NTHREADS];
        f4 b5 = lp4[i + 5 * NTHREADS];
        f4 b6 = lp4[i + 6 * NTHREADS];
        f4 b7 = lp4[i + 7 * NTHREADS];
        acc += remap_sq4(a0, b0);
        acc += remap_sq4(a1, b1);
        acc += remap_sq4(a2, b2);
        acc += remap_sq4(a3, b3);
        acc += remap_sq4(a4, b4);
        acc += remap_sq4(a5, b5);
        acc += remap_sq4(a6, b6);
        acc += remap_sq4(a7, b7);
    }
    // f4 remainder within chunk (not hit at this size — defensive)
    for (; i < end; i += NTHREADS) {
        f4 a = __builtin_nontemporal_load(&np4[i]);
        f4 b = lp4[i];
        acc += remap_sq4(a, b);
    }
    // scalar global remainder (n % 4 != 0 — defensive, block 0 only)
    if (blockIdx.x == 0)
        for (size_t j = n4 * 4 + threadIdx.x; j < n; j += NTHREADS)
            acc += remap_sq(norms[j], labels[j]);

    // wave-64 butterfly reduction
#pragma unroll
    for (int off = 32; off > 0; off >>= 1)
        acc += __shfl_down(acc, off, 64);

    __shared__ float wsum[4];                // 256 threads = 4 waves
    int lane = threadIdx.x & 63;
    int wid  = threadIdx.x >> 6;
    if (lane == 0) wsum[wid] = acc;
    __syncthreads();

    if (threadIdx.x == 0)
        partials[blockIdx.x] = (wsum[0] + wsum[1]) + (wsum[2] + wsum[3]);
}

__global__ __launch_bounds__(NTHREADS) void mse_remap_stage2(
    const float* __restrict__ partials,
    float* __restrict__ out, float inv_n)
{
    // NBLOCKS=2048 floats = 512 float4; 256 threads x 2 float4 each.
    const f4* p4 = reinterpret_cast<const f4*>(partials);
    f4 v0 = p4[threadIdx.x];
    f4 v1 = p4[threadIdx.x + 256];
    float acc = (v0.x + v0.y) + (v0.z + v0.w)
              + (v1.x + v1.y) + (v1.z + v1.w);

#pragma unroll
    for (int off = 32; off > 0; off >>= 1)
        acc += __shfl_down(acc, off, 64);

    __shared__ float wsum[4];
    int lane = threadIdx.x & 63;
    int wid  = threadIdx.x >> 6;
    if (lane == 0) wsum[wid] = acc;
    __syncthreads();

    if (threadIdx.x == 0)
        out[0] = ((wsum[0] + wsum[1]) + (wsum[2] + wsum[3])) * inv_n;
}

extern "C" void kernel_launch(void* const* d_in, const int* in_sizes, int n_in,
                              void* d_out, int out_size, void* d_ws, size_t ws_size,
                              hipStream_t stream)
{
    const float* norms  = (const float*)d_in[0];
    const float* labels = (const float*)d_in[1];
    float* out      = (float*)d_out;
    float* partials = (float*)d_ws;          // 2048 floats = 8 KB scratch

    size_t n  = (size_t)in_sizes[0];         // 4096*8192 = 33,554,432
    size_t n4 = n / 4;                       // 8,388,608 f4
    size_t chunk = (n4 + NBLOCKS - 1) / NBLOCKS;   // 4096 f4 = 64 KB per block
    float inv_n = 1.0f / (float)n;

    mse_remap_stage1<<<NBLOCKS, NTHREADS, 0, stream>>>(norms, labels, partials,
                                                       n4, n, chunk);
    mse_remap_stage2<<<1, NTHREADS, 0, stream>>>(partials, out, inv_n);
}

// Round 12
// 264.290 us; speedup vs baseline: 1.0496x; 1.0075x over previous
//
#include <hip/hip_runtime.h>

// MSE over remapped (norms, labels):
//   label==1: n *= 10, target = 10
//   label==2: n *= 5,  target = 20
//   else:     n *= 1,  target = 0
// out[0] = mean((n - target)^2) over 4096*8192 f32 elements.
//
// Ladder: naive 105 -> x4 101 -> +nt ~84 -> x8 flat -> 2-stage flat ->
// chunked+nt ~75 (250.6 total, BEST) -> chunked+cached 107 (allocate wall
// 2.5 TB/s) -> mixed nt/cached 79 (NO additivity -> shared L2-MSHR wall).
// This round: norms nt (L2 MSHR pool) + labels inline-asm sc1 (L2-BYPASS,
// straight to L3 where labels are ~resident; TCC-side tracking pool).
// Tests whether the two tracking pools can run in parallel.

typedef float f4 __attribute__((ext_vector_type(4)));

#define NBLOCKS 2048
#define NTHREADS 256

__device__ __forceinline__ float remap_sq(float n, float lab) {
    float sn  = (lab == 1.0f) ? 10.0f : ((lab == 2.0f) ? 5.0f : 1.0f);
    float tgt = lab * 10.0f;                 // 0 / 10 / 20
    float d   = fmaf(n, sn, -tgt);
    return d * d;
}

__device__ __forceinline__ float remap_sq4(f4 n, f4 l) {
    return remap_sq(n.x, l.x) + remap_sq(n.y, l.y)
         + remap_sq(n.z, l.z) + remap_sq(n.w, l.w);
}

__global__ __launch_bounds__(NTHREADS) void mse_remap_stage1(
    const float* __restrict__ norms,
    const float* __restrict__ labels,
    float* __restrict__ partials,        // d_ws, one slot per block
    size_t n4, size_t n, size_t chunk)   // chunk = f4 elements per block
{
    const f4* np4 = reinterpret_cast<const f4*>(norms);
    const f4* lp4 = reinterpret_cast<const f4*>(labels);

    size_t base = (size_t)blockIdx.x * chunk;
    size_t end  = base + chunk; if (end > n4) end = n4;

    float acc = 0.0f;
    size_t i = base + threadIdx.x;

    // 8 contiguous block-iterations batched. Norms: nontemporal builtin
    // (issued first, stays above the asm due to its memory clobber).
    // Labels: 8x global_load_dwordx4 sc1 (L2-bypass) + vmcnt(0) in ONE asm
    // block -> all 16 loads outstanding together, all complete at asm end.
    for (; i + 7 * NTHREADS < end; i += 8 * NTHREADS) {
        f4 a0 = __builtin_nontemporal_load(&np4[i]);
        f4 a1 = __builtin_nontemporal_load(&np4[i + 1 * NTHREADS]);
        f4 a2 = __builtin_nontemporal_load(&np4[i + 2 * NTHREADS]);
        f4 a3 = __builtin_nontemporal_load(&np4[i + 3 * NTHREADS]);
        f4 a4 = __builtin_nontemporal_load(&np4[i + 4 * NTHREADS]);
        f4 a5 = __builtin_nontemporal_load(&np4[i + 5 * NTHREADS]);
        f4 a6 = __builtin_nontemporal_load(&np4[i + 6 * NTHREADS]);
        f4 a7 = __builtin_nontemporal_load(&np4[i + 7 * NTHREADS]);

        f4 b0, b1, b2, b3, b4, b5, b6, b7;
        const f4* p0 = &lp4[i];
        const f4* p1 = &lp4[i + 1 * NTHREADS];
        const f4* p2 = &lp4[i + 2 * NTHREADS];
        const f4* p3 = &lp4[i + 3 * NTHREADS];
        const f4* p4 = &lp4[i + 4 * NTHREADS];
        const f4* p5 = &lp4[i + 5 * NTHREADS];
        const f4* p6 = &lp4[i + 6 * NTHREADS];
        const f4* p7 = &lp4[i + 7 * NTHREADS];
        asm volatile(
            "global_load_dwordx4 %[b0], %[p0], off sc1\n\t"
            "global_load_dwordx4 %[b1], %[p1], off sc1\n\t"
            "global_load_dwordx4 %[b2], %[p2], off sc1\n\t"
            "global_load_dwordx4 %[b3], %[p3], off sc1\n\t"
            "global_load_dwordx4 %[b4], %[p4], off sc1\n\t"
            "global_load_dwordx4 %[b5], %[p5], off sc1\n\t"
            "global_load_dwordx4 %[b6], %[p6], off sc1\n\t"
            "global_load_dwordx4 %[b7], %[p7], off sc1\n\t"
            "s_waitcnt vmcnt(0)"
            : [b0]"=&v"(b0), [b1]"=&v"(b1), [b2]"=&v"(b2), [b3]"=&v"(b3),
              [b4]"=&v"(b4), [b5]"=&v"(b5), [b6]"=&v"(b6), [b7]"=&v"(b7)
            : [p0]"v"(p0), [p1]"v"(p1), [p2]"v"(p2), [p3]"v"(p3),
              [p4]"v"(p4), [p5]"v"(p5), [p6]"v"(p6), [p7]"v"(p7)
            : "memory");

        acc += remap_sq4(a0, b0);
        acc += remap_sq4(a1, b1);
        acc += remap_sq4(a2, b2);
        acc += remap_sq4(a3, b3);
        acc += remap_sq4(a4, b4);
        acc += remap_sq4(a5, b5);
        acc += remap_sq4(a6, b6);
        acc += remap_sq4(a7, b7);
    }
    // f4 remainder within chunk (not hit at this size — defensive)
    for (; i < end; i += NTHREADS) {
        f4 a = __builtin_nontemporal_load(&np4[i]);
        f4 b = lp4[i];
        acc += remap_sq4(a, b);
    }
    // scalar global remainder (n % 4 != 0 — defensive, block 0 only)
    if (blockIdx.x == 0)
        for (size_t j = n4 * 4 + threadIdx.x; j < n; j += NTHREADS)
            acc += remap_sq(norms[j], labels[j]);

    // wave-64 butterfly reduction
#pragma unroll
    for (int off = 32; off > 0; off >>= 1)
        acc += __shfl_down(acc, off, 64);

    __shared__ float wsum[4];                // 256 threads = 4 waves
    int lane = threadIdx.x & 63;
    int wid  = threadIdx.x >> 6;
    if (lane == 0) wsum[wid] = acc;
    __syncthreads();

    if (threadIdx.x == 0)
        partials[blockIdx.x] = (wsum[0] + wsum[1]) + (wsum[2] + wsum[3]);
}

__global__ __launch_bounds__(NTHREADS) void mse_remap_stage2(
    const float* __restrict__ partials,
    float* __restrict__ out, float inv_n)
{
    // NBLOCKS=2048 floats = 512 float4; 256 threads x 2 float4 each.
    const f4* p4 = reinterpret_cast<const f4*>(partials);
    f4 v0 = p4[threadIdx.x];
    f4 v1 = p4[threadIdx.x + 256];
    float acc = (v0.x + v0.y) + (v0.z + v0.w)
              + (v1.x + v1.y) + (v1.z + v1.w);

#pragma unroll
    for (int off = 32; off > 0; off >>= 1)
        acc += __shfl_down(acc, off, 64);

    __shared__ float wsum[4];
    int lane = threadIdx.x & 63;
    int wid  = threadIdx.x >> 6;
    if (lane == 0) wsum[wid] = acc;
    __syncthreads();

    if (threadIdx.x == 0)
        out[0] = ((wsum[0] + wsum[1]) + (wsum[2] + wsum[3])) * inv_n;
}

extern "C" void kernel_launch(void* const* d_in, const int* in_sizes, int n_in,
                              void* d_out, int out_size, void* d_ws, size_t ws_size,
                              hipStream_t stream)
{
    const float* norms  = (const float*)d_in[0];
    const float* labels = (const float*)d_in[1];
    float* out      = (float*)d_out;
    float* partials = (float*)d_ws;          // 2048 floats = 8 KB scratch

    size_t n  = (size_t)in_sizes[0];         // 4096*8192 = 33,554,432
    size_t n4 = n / 4;                       // 8,388,608 f4
    size_t chunk = (n4 + NBLOCKS - 1) / NBLOCKS;   // 4096 f4 = 64 KB per block
    float inv_n = 1.0f / (float)n;

    mse_remap_stage1<<<NBLOCKS, NTHREADS, 0, stream>>>(norms, labels, partials,
                                                       n4, n, chunk);
    mse_remap_stage2<<<1, NTHREADS, 0, stream>>>(partials, out, inv_n);
}

// Round 13
// 249.756 us; speedup vs baseline: 1.1107x; 1.0582x over previous
//
#include <hip/hip_runtime.h>

// MSE over remapped (norms, labels):
//   label==1: n *= 10, target = 10
//   label==2: n *= 5,  target = 20
//   else:     n *= 1,  target = 0
// out[0] = mean((n - target)^2) over 4096*8192 f32 elements.
//
// FINAL (round-9 config, measured optimum 250.6us total / ~75us kernel):
// contiguous 64KB/block chunks + all-nontemporal loads + two-stage reduce.
// Measured ceiling: reads cap at ~3.6 TB/s on this part regardless of
// policy (nt/cached/sc1/mixed), MLP depth, or atomics — the read-return
// tracking path is the structural wall. 268MB / 3.6 TB/s ~= 74us.

typedef float f4 __attribute__((ext_vector_type(4)));

#define NBLOCKS 2048
#define NTHREADS 256

__device__ __forceinline__ float remap_sq(float n, float lab) {
    float sn  = (lab == 1.0f) ? 10.0f : ((lab == 2.0f) ? 5.0f : 1.0f);
    float tgt = lab * 10.0f;                 // 0 / 10 / 20
    float d   = fmaf(n, sn, -tgt);
    return d * d;
}

__device__ __forceinline__ float remap_sq4(f4 n, f4 l) {
    return remap_sq(n.x, l.x) + remap_sq(n.y, l.y)
         + remap_sq(n.z, l.z) + remap_sq(n.w, l.w);
}

__global__ __launch_bounds__(NTHREADS) void mse_remap_stage1(
    const float* __restrict__ norms,
    const float* __restrict__ labels,
    float* __restrict__ partials,        // d_ws, one slot per block
    size_t n4, size_t n, size_t chunk)   // chunk = f4 elements per block
{
    const f4* np4 = reinterpret_cast<const f4*>(norms);
    const f4* lp4 = reinterpret_cast<const f4*>(labels);

    size_t base = (size_t)blockIdx.x * chunk;
    size_t end  = base + chunk; if (end > n4) end = n4;

    float acc = 0.0f;
    size_t i = base + threadIdx.x;

    // Batch 8 block-iterations: 16 nt float4 loads in flight, spanning a
    // contiguous 32KB window per array -> DRAM row-buffer friendly.
    for (; i + 7 * NTHREADS < end; i += 8 * NTHREADS) {
        f4 a0 = __builtin_nontemporal_load(&np4[i]);
        f4 a1 = __builtin_nontemporal_load(&np4[i + 1 * NTHREADS]);
        f4 a2 = __builtin_nontemporal_load(&np4[i + 2 * NTHREADS]);
        f4 a3 = __builtin_nontemporal_load(&np4[i + 3 * NTHREADS]);
        f4 a4 = __builtin_nontemporal_load(&np4[i + 4 * NTHREADS]);
        f4 a5 = __builtin_nontemporal_load(&np4[i + 5 * NTHREADS]);
        f4 a6 = __builtin_nontemporal_load(&np4[i + 6 * NTHREADS]);
        f4 a7 = __builtin_nontemporal_load(&np4[i + 7 * NTHREADS]);
        f4 b0 = __builtin_nontemporal_load(&lp4[i]);
        f4 b1 = __builtin_nontemporal_load(&lp4[i + 1 * NTHREADS]);
        f4 b2 = __builtin_nontemporal_load(&lp4[i + 2 * NTHREADS]);
        f4 b3 = __builtin_nontemporal_load(&lp4[i + 3 * NTHREADS]);
        f4 b4 = __builtin_nontemporal_load(&lp4[i + 4 * NTHREADS]);
        f4 b5 = __builtin_nontemporal_load(&lp4[i + 5 * NTHREADS]);
        f4 b6 = __builtin_nontemporal_load(&lp4[i + 6 * NTHREADS]);
        f4 b7 = __builtin_nontemporal_load(&lp4[i + 7 * NTHREADS]);
        acc += remap_sq4(a0, b0);
        acc += remap_sq4(a1, b1);
        acc += remap_sq4(a2, b2);
        acc += remap_sq4(a3, b3);
        acc += remap_sq4(a4, b4);
        acc += remap_sq4(a5, b5);
        acc += remap_sq4(a6, b6);
        acc += remap_sq4(a7, b7);
    }
    // f4 remainder within chunk (not hit at this size — defensive)
    for (; i < end; i += NTHREADS) {
        f4 a = __builtin_nontemporal_load(&np4[i]);
        f4 b = __builtin_nontemporal_load(&lp4[i]);
        acc += remap_sq4(a, b);
    }
    // scalar global remainder (n % 4 != 0 — defensive, block 0 only)
    if (blockIdx.x == 0)
        for (size_t j = n4 * 4 + threadIdx.x; j < n; j += NTHREADS)
            acc += remap_sq(norms[j], labels[j]);

    // wave-64 butterfly reduction
#pragma unroll
    for (int off = 32; off > 0; off >>= 1)
        acc += __shfl_down(acc, off, 64);

    __shared__ float wsum[4];                // 256 threads = 4 waves
    int lane = threadIdx.x & 63;
    int wid  = threadIdx.x >> 6;
    if (lane == 0) wsum[wid] = acc;
    __syncthreads();

    if (threadIdx.x == 0)
        partials[blockIdx.x] = (wsum[0] + wsum[1]) + (wsum[2] + wsum[3]);
}

__global__ __launch_bounds__(NTHREADS) void mse_remap_stage2(
    const float* __restrict__ partials,
    float* __restrict__ out, float inv_n)
{
    // NBLOCKS=2048 floats = 512 float4; 256 threads x 2 float4 each.
    const f4* p4 = reinterpret_cast<const f4*>(partials);
    f4 v0 = p4[threadIdx.x];
    f4 v1 = p4[threadIdx.x + 256];
    float acc = (v0.x + v0.y) + (v0.z + v0.w)
              + (v1.x + v1.y) + (v1.z + v1.w);

#pragma unroll
    for (int off = 32; off > 0; off >>= 1)
        acc += __shfl_down(acc, off, 64);

    __shared__ float wsum[4];
    int lane = threadIdx.x & 63;
    int wid  = threadIdx.x >> 6;
    if (lane == 0) wsum[wid] = acc;
    __syncthreads();

    if (threadIdx.x == 0)
        out[0] = ((wsum[0] + wsum[1]) + (wsum[2] + wsum[3])) * inv_n;
}

extern "C" void kernel_launch(void* const* d_in, const int* in_sizes, int n_in,
                              void* d_out, int out_size, void* d_ws, size_t ws_size,
                              hipStream_t stream)
{
    const float* norms  = (const float*)d_in[0];
    const float* labels = (const float*)d_in[1];
    float* out      = (float*)d_out;
    float* partials = (float*)d_ws;          // 2048 floats = 8 KB scratch

    size_t n  = (size_t)in_sizes[0];         // 4096*8192 = 33,554,432
    size_t n4 = n / 4;                       // 8,388,608 f4
    size_t chunk = (n4 + NBLOCKS - 1) / NBLOCKS;   // 4096 f4 = 64 KB per block
    float inv_n = 1.0f / (float)n;

    mse_remap_stage1<<<NBLOCKS, NTHREADS, 0, stream>>>(norms, labels, partials,
                                                       n4, n, chunk);
    mse_remap_stage2<<<1, NTHREADS, 0, stream>>>(partials, out, inv_n);
}